// Round 1
// baseline (6382.610 us; speedup 1.0000x reference)
//
#include <hip/hip_runtime.h>
#include <math.h>

// Problem constants
#define B_  128
#define T_  512
#define W_  64
#define D_  128
#define C_  256
#define K_  12
#define TP_ 500           // T - K_STEPS
#define G3  768           // 3*C
#define N_SAMPLES 768000  // K_ * TP_ * B_

// ---------------------------------------------------------------------------
// Kernel 1: z_seq = l2norm(rr_windows @ We + be)   (one block per (b,t) row)
// ---------------------------------------------------------------------------
__global__ __launch_bounds__(128) void z_kernel(const float* __restrict__ rr,
                                                const float* __restrict__ We,
                                                const float* __restrict__ be,
                                                float* __restrict__ z_out) {
  int row = blockIdx.x;   // b*T + t   (65536)
  int d   = threadIdx.x;  // 0..127
  __shared__ float s_rr[64];
  __shared__ float s_red[128];
  if (d < 64) s_rr[d] = rr[row * 64 + d];
  __syncthreads();
  float acc = be[d];
#pragma unroll
  for (int w = 0; w < 64; ++w) acc = fmaf(s_rr[w], We[w * 128 + d], acc);
  s_red[d] = acc * acc;
  __syncthreads();
#pragma unroll
  for (int s = 64; s > 0; s >>= 1) {
    if (d < s) s_red[d] += s_red[d + s];
    __syncthreads();
  }
  float inv = 1.0f / fmaxf(sqrtf(s_red[0]), 1e-12f);
  z_out[row * 128 + d] = acc * inv;
}

// ---------------------------------------------------------------------------
// Kernel 2: x_proj = z_seq @ Wi + bi   (65536x128 @ 128x768)
// 128x128 tile per block, K in 4 panels of 32. fp32 register tile 8x8.
// ---------------------------------------------------------------------------
__global__ __launch_bounds__(256) void xproj_kernel(const float* __restrict__ z,
                                                    const float* __restrict__ Wi,
                                                    const float* __restrict__ bi,
                                                    float* __restrict__ xp) {
  __shared__ float sA[128 * 34];   // A panel [128 rows][32 k], stride 34 (2-way max)
  __shared__ float sB[32 * 132];   // B panel [32 k][128 cols], stride 132
  int rb  = blockIdx.x * 128;
  int cb  = blockIdx.y * 128;
  int tid = threadIdx.x;
  int rg  = tid >> 4;   // 0..15
  int cg  = tid & 15;   // 0..15
  float acc[8][8];
#pragma unroll
  for (int i = 0; i < 8; ++i)
#pragma unroll
    for (int j = 0; j < 8; ++j) acc[i][j] = 0.f;

  for (int kp = 0; kp < 4; ++kp) {
    int k0 = kp * 32;
    // A: rows rb..rb+127, cols k0..k0+31 (float2 loads; z base is 8B-aligned only)
#pragma unroll
    for (int it = 0; it < 8; ++it) {
      int i  = tid + it * 256;   // 0..2047
      int r  = i >> 4;
      int c2 = (i & 15) * 2;
      float2 v = *(const float2*)(z + (size_t)(rb + r) * 128 + k0 + c2);
      sA[r * 34 + c2]     = v.x;
      sA[r * 34 + c2 + 1] = v.y;
    }
    // B: Wi rows k0..k0+31, cols cb..cb+127 (float4)
#pragma unroll
    for (int it = 0; it < 4; ++it) {
      int i  = tid + it * 256;   // 0..1023
      int r  = i >> 5;
      int c4 = (i & 31) * 4;
      float4 v = *(const float4*)(Wi + (size_t)(k0 + r) * 768 + cb + c4);
      *(float4*)(&sB[r * 132 + c4]) = v;
    }
    __syncthreads();
#pragma unroll
    for (int kk = 0; kk < 32; ++kk) {
      float a[8], b[8];
#pragma unroll
      for (int i = 0; i < 8; ++i) a[i] = sA[(rg * 8 + i) * 34 + kk];
      float4 b0 = *(const float4*)(&sB[kk * 132 + cg * 8]);
      float4 b1 = *(const float4*)(&sB[kk * 132 + cg * 8 + 4]);
      b[0] = b0.x; b[1] = b0.y; b[2] = b0.z; b[3] = b0.w;
      b[4] = b1.x; b[5] = b1.y; b[6] = b1.z; b[7] = b1.w;
#pragma unroll
      for (int i = 0; i < 8; ++i)
#pragma unroll
        for (int j = 0; j < 8; ++j) acc[i][j] = fmaf(a[i], b[j], acc[i][j]);
    }
    __syncthreads();
  }
  // epilogue + bias
#pragma unroll
  for (int i = 0; i < 8; ++i) {
    int row = rb + rg * 8 + i;
#pragma unroll
    for (int j = 0; j < 8; ++j) {
      int col = cb + cg * 8 + j;
      xp[(size_t)row * 768 + col] = acc[i][j] + bi[col];
    }
  }
}

// ---------------------------------------------------------------------------
// Kernel 3: GRU scan. 64 blocks x 768 threads; 2 batch rows per block.
// Wh streamed from L2 each step (786KB); h/x/gates in LDS.
// ---------------------------------------------------------------------------
__global__ __launch_bounds__(768) void gru_kernel(const float* __restrict__ xp,
                                                  const float* __restrict__ Wh,
                                                  const float* __restrict__ bh,
                                                  float* __restrict__ c_out) {
  __shared__ float h[2][256];
  __shared__ float xg[2][768];
  __shared__ float hg[2][768];
  int j  = threadIdx.x;         // 0..767 (gate column)
  int b0 = blockIdx.x * 2;
  if (j < 512) h[j >> 8][j & 255] = 0.f;
  float bhj = bh[j];
  __syncthreads();

  for (int t = 0; t < 512; ++t) {
    float x0 = xp[((size_t)b0 * 512 + t) * 768 + j];
    float x1 = xp[((size_t)(b0 + 1) * 512 + t) * 768 + j];
    float a0 = bhj, a1 = bhj;
    const float* wcol = Wh + j;
#pragma unroll 8
    for (int c = 0; c < 256; ++c) {
      float w = wcol[c * 768];
      a0 = fmaf(h[0][c], w, a0);
      a1 = fmaf(h[1][c], w, a1);
    }
    xg[0][j] = x0; xg[1][j] = x1;
    hg[0][j] = a0; hg[1][j] = a1;
    __syncthreads();
    if (j < 256) {
#pragma unroll
      for (int b = 0; b < 2; ++b) {
        float xr = xg[b][j], xz = xg[b][j + 256], xn = xg[b][j + 512];
        float hr = hg[b][j], hz = hg[b][j + 256], hn = hg[b][j + 512];
        float r  = 1.f / (1.f + __expf(-(xr + hr)));
        float zz = 1.f / (1.f + __expf(-(xz + hz)));
        float n  = tanhf(xn + r * hn);
        float hnew = (1.f - zz) * n + zz * h[b][j];
        h[b][j] = hnew;
        c_out[((size_t)(b0 + b) * 512 + t) * 256 + j] = hnew;
      }
    }
    __syncthreads();
  }
}

// ---------------------------------------------------------------------------
// Kernel 4: fused pred -> l2norm -> logits -> lse/diag/argmax -> loss/acc.
// One block per (t, k); never materializes pred or logits in HBM.
// Thread tile: rows b = rg*8+i, cols c (or d) = cg + 16*j (conflict-free LDS).
// ---------------------------------------------------------------------------
__global__ __launch_bounds__(256) void cpc_kernel(const float* __restrict__ z,
                                                  const float* __restrict__ c_seq,
                                                  const float* __restrict__ Wk_w,
                                                  const float* __restrict__ Wk_b,
                                                  float* __restrict__ out) {
  int t   = blockIdx.x;   // 0..499
  int k   = blockIdx.y;   // 0..11
  int tid = threadIdx.x;
  int rg  = tid >> 4;
  int cg  = tid & 15;

  __shared__ float sA[128 * 34];     // Ct panel (phase B) / P panel (phase D)
  __shared__ float sB[128 * 34];     // Wk panel [32][132] fits / Zf panel [128][34]
  __shared__ float red1[128 * 17];
  __shared__ float red2[128 * 17];
  __shared__ float s_scale[128];
  __shared__ float s_rowmax[128];
  __shared__ float s_diag[128];
  __shared__ float s_loss, s_corr;

  if (tid == 0) { s_loss = 0.f; s_corr = 0.f; }

  float p[8][8];
#pragma unroll
  for (int i = 0; i < 8; ++i)
#pragma unroll
    for (int j = 0; j < 8; ++j) p[i][j] = 0.f;

  // ---- Phase B: P[b][d] = c_seq[:,t,:] @ Wk_w[k]  (8 panels of 32 over C) ----
  for (int cp = 0; cp < 8; ++cp) {
    int c0 = cp * 32;
#pragma unroll
    for (int it = 0; it < 8; ++it) {
      int i  = tid + it * 256;
      int r  = i >> 4;
      int c2 = (i & 15) * 2;
      float2 v = *(const float2*)(c_seq + ((size_t)r * 512 + t) * 256 + c0 + c2);
      sA[r * 34 + c2]     = v.x;
      sA[r * 34 + c2 + 1] = v.y;
    }
#pragma unroll
    for (int it = 0; it < 4; ++it) {
      int i  = tid + it * 256;
      int r  = i >> 5;
      int c4 = (i & 31) * 4;
      float4 v = *(const float4*)(Wk_w + ((size_t)k * 256 + c0 + r) * 128 + c4);
      *(float4*)(&sB[r * 132 + c4]) = v;
    }
    __syncthreads();
#pragma unroll
    for (int cc = 0; cc < 32; ++cc) {
      float a[8], b[8];
#pragma unroll
      for (int i = 0; i < 8; ++i) a[i] = sA[(rg * 8 + i) * 34 + cc];
#pragma unroll
      for (int j = 0; j < 8; ++j) b[j] = sB[cc * 132 + cg + 16 * j];
#pragma unroll
      for (int i = 0; i < 8; ++i)
#pragma unroll
        for (int j = 0; j < 8; ++j) p[i][j] = fmaf(a[i], b[j], p[i][j]);
    }
    __syncthreads();
  }

  // bias + row sum-of-squares
#pragma unroll
  for (int j = 0; j < 8; ++j) {
    float bb = Wk_b[k * 128 + cg + 16 * j];
#pragma unroll
    for (int i = 0; i < 8; ++i) p[i][j] += bb;
  }
#pragma unroll
  for (int i = 0; i < 8; ++i) {
    float ss = 0.f;
#pragma unroll
    for (int j = 0; j < 8; ++j) ss = fmaf(p[i][j], p[i][j], ss);
    red1[(rg * 8 + i) * 17 + cg] = ss;
  }
  __syncthreads();
  if (tid < 128) {
    float ss = 0.f;
#pragma unroll
    for (int g = 0; g < 16; ++g) ss += red1[tid * 17 + g];
    s_scale[tid] = 10.0f / fmaxf(sqrtf(ss), 1e-12f);   // 1/TEMP folded in
  }
  __syncthreads();

  // ---- Phase D: logits[b][c] = scale[b]*P[b][:] . Zf[c][:]  (4 d-panels) ----
  float lacc[8][8];
#pragma unroll
  for (int i = 0; i < 8; ++i)
#pragma unroll
    for (int j = 0; j < 8; ++j) lacc[i][j] = 0.f;
  int tz = t + k + 1;
#pragma unroll
  for (int dp = 0; dp < 4; ++dp) {
    // write scaled P panel: this thread owns local cols {cg, cg+16}
#pragma unroll
    for (int jj = 0; jj < 2; ++jj) {
      int j = 2 * dp + jj;
#pragma unroll
      for (int i = 0; i < 8; ++i) {
        int b = rg * 8 + i;
        sA[b * 34 + cg + 16 * jj] = p[i][j] * s_scale[b];
      }
    }
    // Zf panel: 128 rows x 32 d
#pragma unroll
    for (int it = 0; it < 8; ++it) {
      int i  = tid + it * 256;
      int r  = i >> 4;
      int c2 = (i & 15) * 2;
      float2 v = *(const float2*)(z + ((size_t)r * 512 + tz) * 128 + 32 * dp + c2);
      sB[r * 34 + c2]     = v.x;
      sB[r * 34 + c2 + 1] = v.y;
    }
    __syncthreads();
#pragma unroll
    for (int dd = 0; dd < 32; ++dd) {
      float a[8], b[8];
#pragma unroll
      for (int i = 0; i < 8; ++i) a[i] = sA[(rg * 8 + i) * 34 + dd];
#pragma unroll
      for (int j = 0; j < 8; ++j) b[j] = sB[(cg + 16 * j) * 34 + dd];
#pragma unroll
      for (int i = 0; i < 8; ++i)
#pragma unroll
        for (int j = 0; j < 8; ++j) lacc[i][j] = fmaf(a[i], b[j], lacc[i][j]);
    }
    __syncthreads();
  }

  // diag
#pragma unroll
  for (int i = 0; i < 8; ++i) {
    int b = rg * 8 + i;
#pragma unroll
    for (int j = 0; j < 8; ++j) {
      int c = cg + 16 * j;
      if (c == b) s_diag[b] = lacc[i][j];
    }
  }

  // local max / argmax per row
#pragma unroll
  for (int i = 0; i < 8; ++i) {
    float m = -1e30f; int mi = 1 << 30;
#pragma unroll
    for (int j = 0; j < 8; ++j) {
      int c = cg + 16 * j;     // ascending in j
      float v = lacc[i][j];
      if (v > m) { m = v; mi = c; }
    }
    red1[(rg * 8 + i) * 17 + cg] = m;
    red2[(rg * 8 + i) * 17 + cg] = (float)mi;
  }
  __syncthreads();
  float rmax = -1e30f; int ridx = 1 << 30;
  if (tid < 128) {
#pragma unroll
    for (int g = 0; g < 16; ++g) {
      float v = red1[tid * 17 + g];
      int  ix = (int)red2[tid * 17 + g];
      if (v > rmax || (v == rmax && ix < ridx)) { rmax = v; ridx = ix; }
    }
    s_rowmax[tid] = rmax;
  }
  __syncthreads();
  // sum of exp(l - rowmax)
#pragma unroll
  for (int i = 0; i < 8; ++i) {
    int b = rg * 8 + i;
    float rm = s_rowmax[b];
    float e = 0.f;
#pragma unroll
    for (int j = 0; j < 8; ++j) e += __expf(lacc[i][j] - rm);
    red1[b * 17 + cg] = e;
  }
  __syncthreads();
  if (tid < 128) {
    float se = 0.f;
#pragma unroll
    for (int g = 0; g < 16; ++g) se += red1[tid * 17 + g];
    float lse  = s_rowmax[tid] + __logf(se);
    float loss = lse - s_diag[tid];
    atomicAdd(&s_loss, loss);
    atomicAdd(&s_corr, (ridx == tid) ? 1.0f : 0.0f);
  }
  __syncthreads();
  if (tid == 0) {
    atomicAdd(out + 0, s_loss * (float)(1.0 / (double)N_SAMPLES));
    atomicAdd(out + 1, s_corr * (float)(100.0 / (double)N_SAMPLES));
  }
}

// ---------------------------------------------------------------------------
extern "C" void kernel_launch(void* const* d_in, const int* in_sizes, int n_in,
                              void* d_out, int out_size, void* d_ws, size_t ws_size,
                              hipStream_t stream) {
  (void)in_sizes; (void)n_in; (void)out_size; (void)ws_size;
  const float* rr  = (const float*)d_in[0];
  const float* We  = (const float*)d_in[1];
  const float* be  = (const float*)d_in[2];
  const float* Wi  = (const float*)d_in[3];
  const float* Wh  = (const float*)d_in[4];
  const float* bi  = (const float*)d_in[5];
  const float* bh  = (const float*)d_in[6];
  const float* Wkw = (const float*)d_in[7];
  const float* Wkb = (const float*)d_in[8];

  float* out = (float*)d_out;
  float* z   = out + 2;                              // (B,T,D) fp32
  float* c   = z + (size_t)B_ * T_ * D_;             // (B,T,C) fp32
  float* xp  = (float*)d_ws;                         // (B,T,3C) fp32, 201MB

  hipMemsetAsync(d_out, 0, 2 * sizeof(float), stream);
  z_kernel<<<B_ * T_, 128, 0, stream>>>(rr, We, be, z);
  xproj_kernel<<<dim3(512, 6), 256, 0, stream>>>(z, Wi, bi, xp);
  gru_kernel<<<B_ / 2, 768, 0, stream>>>(xp, Wh, bh, c);
  cpc_kernel<<<dim3(TP_, K_), 256, 0, stream>>>(z, c, Wkw, Wkb, out);
}

// Round 2
// 2818.624 us; speedup vs baseline: 2.2644x; 2.2644x over previous
//
#include <hip/hip_runtime.h>
#include <math.h>

// Problem constants
#define B_  128
#define T_  512
#define W_  64
#define D_  128
#define C_  256
#define K_  12
#define TP_ 500           // T - K_STEPS
#define G3  768           // 3*C
#define N_SAMPLES 768000  // K_ * TP_ * B_

typedef _Float16 half2v __attribute__((ext_vector_type(2)));

#if defined(__has_builtin)
#if __has_builtin(__builtin_amdgcn_fdot2)
#define HAVE_FDOT2 1
#endif
#endif

__device__ __forceinline__ float dot2acc(unsigned int wu, unsigned int hu, float acc) {
#ifdef HAVE_FDOT2
  return __builtin_amdgcn_fdot2(__builtin_bit_cast(half2v, wu),
                                __builtin_bit_cast(half2v, hu), acc, false);
#else
  half2v w = __builtin_bit_cast(half2v, wu);
  half2v h = __builtin_bit_cast(half2v, hu);
  acc = fmaf((float)w.x, (float)h.x, acc);
  return fmaf((float)w.y, (float)h.y, acc);
#endif
}

__device__ __forceinline__ unsigned int pack2(float a, float b) {
  unsigned short ua = __builtin_bit_cast(unsigned short, (_Float16)a);
  unsigned short ub = __builtin_bit_cast(unsigned short, (_Float16)b);
  return (unsigned int)ua | ((unsigned int)ub << 16);
}

// ---------------------------------------------------------------------------
// Kernel 1: z_seq = l2norm(rr_windows @ We + be)   (one block per (b,t) row)
// ---------------------------------------------------------------------------
__global__ __launch_bounds__(128) void z_kernel(const float* __restrict__ rr,
                                                const float* __restrict__ We,
                                                const float* __restrict__ be,
                                                float* __restrict__ z_out) {
  int row = blockIdx.x;   // b*T + t   (65536)
  int d   = threadIdx.x;  // 0..127
  __shared__ float s_rr[64];
  __shared__ float s_red[128];
  if (d < 64) s_rr[d] = rr[row * 64 + d];
  __syncthreads();
  float acc = be[d];
#pragma unroll
  for (int w = 0; w < 64; ++w) acc = fmaf(s_rr[w], We[w * 128 + d], acc);
  s_red[d] = acc * acc;
  __syncthreads();
#pragma unroll
  for (int s = 64; s > 0; s >>= 1) {
    if (d < s) s_red[d] += s_red[d + s];
    __syncthreads();
  }
  float inv = 1.0f / fmaxf(sqrtf(s_red[0]), 1e-12f);
  z_out[row * 128 + d] = acc * inv;
}

// ---------------------------------------------------------------------------
// Kernel 2: x_proj = z_seq @ Wi + bi   (65536x128 @ 128x768), stored as f16
// ---------------------------------------------------------------------------
__global__ __launch_bounds__(256) void xproj_kernel(const float* __restrict__ z,
                                                    const float* __restrict__ Wi,
                                                    const float* __restrict__ bi,
                                                    _Float16* __restrict__ xp) {
  __shared__ float sA[128 * 34];   // A panel [128 rows][32 k]
  __shared__ float sB[32 * 132];   // B panel [32 k][128 cols]
  int rb  = blockIdx.x * 128;
  int cb  = blockIdx.y * 128;
  int tid = threadIdx.x;
  int rg  = tid >> 4;   // 0..15
  int cg  = tid & 15;   // 0..15
  float acc[8][8];
#pragma unroll
  for (int i = 0; i < 8; ++i)
#pragma unroll
    for (int j = 0; j < 8; ++j) acc[i][j] = 0.f;

  for (int kp = 0; kp < 4; ++kp) {
    int k0 = kp * 32;
#pragma unroll
    for (int it = 0; it < 8; ++it) {
      int i  = tid + it * 256;   // 0..2047
      int r  = i >> 4;
      int c2 = (i & 15) * 2;
      float2 v = *(const float2*)(z + (size_t)(rb + r) * 128 + k0 + c2);
      sA[r * 34 + c2]     = v.x;
      sA[r * 34 + c2 + 1] = v.y;
    }
#pragma unroll
    for (int it = 0; it < 4; ++it) {
      int i  = tid + it * 256;   // 0..1023
      int r  = i >> 5;
      int c4 = (i & 31) * 4;
      float4 v = *(const float4*)(Wi + (size_t)(k0 + r) * 768 + cb + c4);
      *(float4*)(&sB[r * 132 + c4]) = v;
    }
    __syncthreads();
#pragma unroll
    for (int kk = 0; kk < 32; ++kk) {
      float a[8], b[8];
#pragma unroll
      for (int i = 0; i < 8; ++i) a[i] = sA[(rg * 8 + i) * 34 + kk];
      float4 b0 = *(const float4*)(&sB[kk * 132 + cg * 8]);
      float4 b1 = *(const float4*)(&sB[kk * 132 + cg * 8 + 4]);
      b[0] = b0.x; b[1] = b0.y; b[2] = b0.z; b[3] = b0.w;
      b[4] = b1.x; b[5] = b1.y; b[6] = b1.z; b[7] = b1.w;
#pragma unroll
      for (int i = 0; i < 8; ++i)
#pragma unroll
        for (int j = 0; j < 8; ++j) acc[i][j] = fmaf(a[i], b[j], acc[i][j]);
    }
    __syncthreads();
  }
#pragma unroll
  for (int i = 0; i < 8; ++i) {
    int row = rb + rg * 8 + i;
#pragma unroll
    for (int j = 0; j < 8; ++j) {
      int col = cb + cg * 8 + j;
      xp[(size_t)row * 768 + col] = (_Float16)(acc[i][j] + bi[col]);
    }
  }
}

// ---------------------------------------------------------------------------
// Kernel 2b: WhT_f16[j][c-pair] packed u32:  lo=f16(Wh[2i][j]), hi=f16(Wh[2i+1][j])
// ---------------------------------------------------------------------------
__global__ __launch_bounds__(256) void whT_kernel(const float* __restrict__ Wh,
                                                  unsigned int* __restrict__ whT) {
  int g = blockIdx.x * 256 + threadIdx.x;  // 0..98303
  int i = g / 768;                          // pair index 0..127
  int j = g % 768;                          // column 0..767
  float lo = Wh[(size_t)(2 * i) * 768 + j];
  float hi = Wh[(size_t)(2 * i + 1) * 768 + j];
  whT[(size_t)j * 128 + i] = pack2(lo, hi);
}

// ---------------------------------------------------------------------------
// Kernel 3: GRU scan. 128 blocks x 768 threads; 1 batch row per block.
// Wh (f16, transposed) register-resident: thread j owns gate-column j
// (256 c-values = 128 packed u32 VGPRs). h packed f16x2 in LDS (broadcast).
// fp32 h state carried in owner-thread registers (threads 0..127 own c=2j,2j+1).
// ---------------------------------------------------------------------------
__global__ __launch_bounds__(768) void gru_kernel(const _Float16* __restrict__ xp,
                                                  const unsigned int* __restrict__ whT,
                                                  const float* __restrict__ bh,
                                                  float* __restrict__ c_out) {
  __shared__ __align__(16) unsigned int s_h2[128];  // h as f16 pairs
  __shared__ float s_hg[768];
  __shared__ float s_xg[768];
  int j = threadIdx.x;          // gate column 0..767
  int b = blockIdx.x;           // batch row

  // load this column's weights into registers (contiguous 512B per thread)
  unsigned int w[128];
  const uint4* wsrc = (const uint4*)(whT + (size_t)j * 128);
#pragma unroll
  for (int i = 0; i < 32; ++i) {
    uint4 v = wsrc[i];
    w[4 * i + 0] = v.x; w[4 * i + 1] = v.y; w[4 * i + 2] = v.z; w[4 * i + 3] = v.w;
  }

  if (j < 128) s_h2[j] = 0u;
  float bhj = bh[j];
  float h0 = 0.f, h1 = 0.f;     // fp32 h state for c=2j,2j+1 (threads 0..127)
  const _Float16* xrow = xp + (size_t)b * 512 * 768 + j;
  float x_next = (float)xrow[0];
  __syncthreads();

  for (int t = 0; t < 512; ++t) {
    float x_cur = x_next;
    if (t < 511) x_next = (float)xrow[(size_t)(t + 1) * 768];

    float acc = bhj;
    const uint4* h4 = (const uint4*)s_h2;
#pragma unroll
    for (int i = 0; i < 32; ++i) {
      uint4 hh = h4[i];
      acc = dot2acc(w[4 * i + 0], hh.x, acc);
      acc = dot2acc(w[4 * i + 1], hh.y, acc);
      acc = dot2acc(w[4 * i + 2], hh.z, acc);
      acc = dot2acc(w[4 * i + 3], hh.w, acc);
    }
    s_hg[j] = acc;
    s_xg[j] = x_cur;
    __syncthreads();

    if (j < 128) {
      int c0 = 2 * j;
      // c = c0
      float r0 = 1.f / (1.f + __expf(-(s_xg[c0]       + s_hg[c0])));
      float z0 = 1.f / (1.f + __expf(-(s_xg[c0 + 256] + s_hg[c0 + 256])));
      float n0 = tanhf(s_xg[c0 + 512] + r0 * s_hg[c0 + 512]);
      h0 = (1.f - z0) * n0 + z0 * h0;
      // c = c0+1
      float r1 = 1.f / (1.f + __expf(-(s_xg[c0 + 1]   + s_hg[c0 + 1])));
      float z1 = 1.f / (1.f + __expf(-(s_xg[c0 + 257] + s_hg[c0 + 257])));
      float n1 = tanhf(s_xg[c0 + 513] + r1 * s_hg[c0 + 513]);
      h1 = (1.f - z1) * n1 + z1 * h1;

      s_h2[j] = pack2(h0, h1);
      *(float2*)(c_out + ((size_t)b * 512 + t) * 256 + c0) = make_float2(h0, h1);
    }
    __syncthreads();
  }
}

// ---------------------------------------------------------------------------
// Kernel 4: fused pred -> l2norm -> logits -> lse/diag/argmax -> loss/acc.
// ---------------------------------------------------------------------------
__global__ __launch_bounds__(256) void cpc_kernel(const float* __restrict__ z,
                                                  const float* __restrict__ c_seq,
                                                  const float* __restrict__ Wk_w,
                                                  const float* __restrict__ Wk_b,
                                                  float* __restrict__ out) {
  int t   = blockIdx.x;   // 0..499
  int k   = blockIdx.y;   // 0..11
  int tid = threadIdx.x;
  int rg  = tid >> 4;
  int cg  = tid & 15;

  __shared__ float sA[128 * 34];
  __shared__ float sB[128 * 34];
  __shared__ float red1[128 * 17];
  __shared__ float red2[128 * 17];
  __shared__ float s_scale[128];
  __shared__ float s_rowmax[128];
  __shared__ float s_diag[128];
  __shared__ float s_loss, s_corr;

  if (tid == 0) { s_loss = 0.f; s_corr = 0.f; }

  float p[8][8];
#pragma unroll
  for (int i = 0; i < 8; ++i)
#pragma unroll
    for (int j = 0; j < 8; ++j) p[i][j] = 0.f;

  // ---- Phase B: P[b][d] = c_seq[:,t,:] @ Wk_w[k] ----
  for (int cp = 0; cp < 8; ++cp) {
    int c0 = cp * 32;
#pragma unroll
    for (int it = 0; it < 8; ++it) {
      int i  = tid + it * 256;
      int r  = i >> 4;
      int c2 = (i & 15) * 2;
      float2 v = *(const float2*)(c_seq + ((size_t)r * 512 + t) * 256 + c0 + c2);
      sA[r * 34 + c2]     = v.x;
      sA[r * 34 + c2 + 1] = v.y;
    }
#pragma unroll
    for (int it = 0; it < 4; ++it) {
      int i  = tid + it * 256;
      int r  = i >> 5;
      int c4 = (i & 31) * 4;
      float4 v = *(const float4*)(Wk_w + ((size_t)k * 256 + c0 + r) * 128 + c4);
      *(float4*)(&sB[r * 132 + c4]) = v;
    }
    __syncthreads();
#pragma unroll
    for (int cc = 0; cc < 32; ++cc) {
      float a[8], b[8];
#pragma unroll
      for (int i = 0; i < 8; ++i) a[i] = sA[(rg * 8 + i) * 34 + cc];
#pragma unroll
      for (int j = 0; j < 8; ++j) b[j] = sB[cc * 132 + cg + 16 * j];
#pragma unroll
      for (int i = 0; i < 8; ++i)
#pragma unroll
        for (int j = 0; j < 8; ++j) p[i][j] = fmaf(a[i], b[j], p[i][j]);
    }
    __syncthreads();
  }

  // bias + row sum-of-squares
#pragma unroll
  for (int j = 0; j < 8; ++j) {
    float bb = Wk_b[k * 128 + cg + 16 * j];
#pragma unroll
    for (int i = 0; i < 8; ++i) p[i][j] += bb;
  }
#pragma unroll
  for (int i = 0; i < 8; ++i) {
    float ss = 0.f;
#pragma unroll
    for (int j = 0; j < 8; ++j) ss = fmaf(p[i][j], p[i][j], ss);
    red1[(rg * 8 + i) * 17 + cg] = ss;
  }
  __syncthreads();
  if (tid < 128) {
    float ss = 0.f;
#pragma unroll
    for (int g = 0; g < 16; ++g) ss += red1[tid * 17 + g];
    s_scale[tid] = 10.0f / fmaxf(sqrtf(ss), 1e-12f);   // 1/TEMP folded in
  }
  __syncthreads();

  // ---- Phase D: logits ----
  float lacc[8][8];
#pragma unroll
  for (int i = 0; i < 8; ++i)
#pragma unroll
    for (int j = 0; j < 8; ++j) lacc[i][j] = 0.f;
  int tz = t + k + 1;
#pragma unroll
  for (int dp = 0; dp < 4; ++dp) {
#pragma unroll
    for (int jj = 0; jj < 2; ++jj) {
      int j = 2 * dp + jj;
#pragma unroll
      for (int i = 0; i < 8; ++i) {
        int b = rg * 8 + i;
        sA[b * 34 + cg + 16 * jj] = p[i][j] * s_scale[b];
      }
    }
#pragma unroll
    for (int it = 0; it < 8; ++it) {
      int i  = tid + it * 256;
      int r  = i >> 4;
      int c2 = (i & 15) * 2;
      float2 v = *(const float2*)(z + ((size_t)r * 512 + tz) * 128 + 32 * dp + c2);
      sB[r * 34 + c2]     = v.x;
      sB[r * 34 + c2 + 1] = v.y;
    }
    __syncthreads();
#pragma unroll
    for (int dd = 0; dd < 32; ++dd) {
      float a[8], b[8];
#pragma unroll
      for (int i = 0; i < 8; ++i) a[i] = sA[(rg * 8 + i) * 34 + dd];
#pragma unroll
      for (int j = 0; j < 8; ++j) b[j] = sB[(cg + 16 * j) * 34 + dd];
#pragma unroll
      for (int i = 0; i < 8; ++i)
#pragma unroll
        for (int j = 0; j < 8; ++j) lacc[i][j] = fmaf(a[i], b[j], lacc[i][j]);
    }
    __syncthreads();
  }

  // diag
#pragma unroll
  for (int i = 0; i < 8; ++i) {
    int b = rg * 8 + i;
#pragma unroll
    for (int j = 0; j < 8; ++j) {
      int c = cg + 16 * j;
      if (c == b) s_diag[b] = lacc[i][j];
    }
  }

  // local max / argmax per row
#pragma unroll
  for (int i = 0; i < 8; ++i) {
    float m = -1e30f; int mi = 1 << 30;
#pragma unroll
    for (int j = 0; j < 8; ++j) {
      int c = cg + 16 * j;
      float v = lacc[i][j];
      if (v > m) { m = v; mi = c; }
    }
    red1[(rg * 8 + i) * 17 + cg] = m;
    red2[(rg * 8 + i) * 17 + cg] = (float)mi;
  }
  __syncthreads();
  float rmax = -1e30f; int ridx = 1 << 30;
  if (tid < 128) {
#pragma unroll
    for (int g = 0; g < 16; ++g) {
      float v = red1[tid * 17 + g];
      int  ix = (int)red2[tid * 17 + g];
      if (v > rmax || (v == rmax && ix < ridx)) { rmax = v; ridx = ix; }
    }
    s_rowmax[tid] = rmax;
  }
  __syncthreads();
#pragma unroll
  for (int i = 0; i < 8; ++i) {
    int b = rg * 8 + i;
    float rm = s_rowmax[b];
    float e = 0.f;
#pragma unroll
    for (int j = 0; j < 8; ++j) e += __expf(lacc[i][j] - rm);
    red1[b * 17 + cg] = e;
  }
  __syncthreads();
  if (tid < 128) {
    float se = 0.f;
#pragma unroll
    for (int g = 0; g < 16; ++g) se += red1[tid * 17 + g];
    float lse  = s_rowmax[tid] + __logf(se);
    float loss = lse - s_diag[tid];
    atomicAdd(&s_loss, loss);
    atomicAdd(&s_corr, (ridx == tid) ? 1.0f : 0.0f);
  }
  __syncthreads();
  if (tid == 0) {
    atomicAdd(out + 0, s_loss * (float)(1.0 / (double)N_SAMPLES));
    atomicAdd(out + 1, s_corr * (float)(100.0 / (double)N_SAMPLES));
  }
}

// ---------------------------------------------------------------------------
extern "C" void kernel_launch(void* const* d_in, const int* in_sizes, int n_in,
                              void* d_out, int out_size, void* d_ws, size_t ws_size,
                              hipStream_t stream) {
  (void)in_sizes; (void)n_in; (void)out_size; (void)ws_size;
  const float* rr  = (const float*)d_in[0];
  const float* We  = (const float*)d_in[1];
  const float* be  = (const float*)d_in[2];
  const float* Wi  = (const float*)d_in[3];
  const float* Wh  = (const float*)d_in[4];
  const float* bi  = (const float*)d_in[5];
  const float* bh  = (const float*)d_in[6];
  const float* Wkw = (const float*)d_in[7];
  const float* Wkb = (const float*)d_in[8];

  float* out = (float*)d_out;
  float* z   = out + 2;                              // (B,T,D) fp32
  float* c   = z + (size_t)B_ * T_ * D_;             // (B,T,C) fp32

  // workspace layout: whT (98304 u32 = 384KB), then xp f16 (B*T*3C = 100.7MB)
  unsigned int* whT = (unsigned int*)d_ws;
  _Float16*     xp  = (_Float16*)((char*)d_ws + 98304 * sizeof(unsigned int));

  hipMemsetAsync(d_out, 0, 2 * sizeof(float), stream);
  z_kernel<<<B_ * T_, 128, 0, stream>>>(rr, We, be, z);
  xproj_kernel<<<dim3(512, 6), 256, 0, stream>>>(z, Wi, bi, xp);
  whT_kernel<<<384, 256, 0, stream>>>(Wh, whT);
  gru_kernel<<<B_, 768, 0, stream>>>(xp, whT, bh, c);
  cpc_kernel<<<dim3(TP_, K_), 256, 0, stream>>>(z, c, Wkw, Wkb, out);
}

// Round 3
// 1777.097 us; speedup vs baseline: 3.5916x; 1.5861x over previous
//
#include <hip/hip_runtime.h>
#include <math.h>

// Problem constants
#define B_  128
#define T_  512
#define W_  64
#define D_  128
#define C_  256
#define K_  12
#define TP_ 500           // T - K_STEPS
#define N_SAMPLES 768000  // K_ * TP_ * B_

typedef _Float16 half2v __attribute__((ext_vector_type(2)));
typedef _Float16 f16x8  __attribute__((ext_vector_type(8)));
typedef float    f32x4  __attribute__((ext_vector_type(4)));

#if defined(__has_builtin)
#if __has_builtin(__builtin_amdgcn_fdot2)
#define HAVE_FDOT2 1
#endif
#endif

__device__ __forceinline__ float dot2acc(unsigned int wu, unsigned int hu, float acc) {
#ifdef HAVE_FDOT2
  return __builtin_amdgcn_fdot2(__builtin_bit_cast(half2v, wu),
                                __builtin_bit_cast(half2v, hu), acc, false);
#else
  half2v w = __builtin_bit_cast(half2v, wu);
  half2v h = __builtin_bit_cast(half2v, hu);
  acc = fmaf((float)w.x, (float)h.x, acc);
  return fmaf((float)w.y, (float)h.y, acc);
#endif
}

__device__ __forceinline__ unsigned int pack2(float a, float b) {
  unsigned short ua = __builtin_bit_cast(unsigned short, (_Float16)a);
  unsigned short ub = __builtin_bit_cast(unsigned short, (_Float16)b);
  return (unsigned int)ua | ((unsigned int)ub << 16);
}

// ---------------------------------------------------------------------------
// Kernel 1: z_seq = l2norm(rr_windows @ We + be); also writes f16 copy z16.
// ---------------------------------------------------------------------------
__global__ __launch_bounds__(128) void z_kernel(const float* __restrict__ rr,
                                                const float* __restrict__ We,
                                                const float* __restrict__ be,
                                                float* __restrict__ z_out,
                                                _Float16* __restrict__ z16) {
  int row = blockIdx.x;   // b*T + t
  int d   = threadIdx.x;  // 0..127
  __shared__ float s_rr[64];
  __shared__ float s_red[128];
  if (d < 64) s_rr[d] = rr[row * 64 + d];
  __syncthreads();
  float acc = be[d];
#pragma unroll
  for (int w = 0; w < 64; ++w) acc = fmaf(s_rr[w], We[w * 128 + d], acc);
  s_red[d] = acc * acc;
  __syncthreads();
#pragma unroll
  for (int s = 64; s > 0; s >>= 1) {
    if (d < s) s_red[d] += s_red[d + s];
    __syncthreads();
  }
  float inv = 1.0f / fmaxf(sqrtf(s_red[0]), 1e-12f);
  float zv = acc * inv;
  z_out[row * 128 + d] = zv;
  z16[(size_t)row * 128 + d] = (_Float16)zv;
}

// ---------------------------------------------------------------------------
// Kernel 2: x_proj = z_seq @ Wi + bi  (stored f16)
// ---------------------------------------------------------------------------
__global__ __launch_bounds__(256) void xproj_kernel(const float* __restrict__ z,
                                                    const float* __restrict__ Wi,
                                                    const float* __restrict__ bi,
                                                    _Float16* __restrict__ xp) {
  __shared__ float sA[128 * 34];
  __shared__ float sB[32 * 132];
  int rb  = blockIdx.x * 128;
  int cb  = blockIdx.y * 128;
  int tid = threadIdx.x;
  int rg  = tid >> 4;
  int cg  = tid & 15;
  float acc[8][8];
#pragma unroll
  for (int i = 0; i < 8; ++i)
#pragma unroll
    for (int j = 0; j < 8; ++j) acc[i][j] = 0.f;

  for (int kp = 0; kp < 4; ++kp) {
    int k0 = kp * 32;
#pragma unroll
    for (int it = 0; it < 8; ++it) {
      int i  = tid + it * 256;
      int r  = i >> 4;
      int c2 = (i & 15) * 2;
      float2 v = *(const float2*)(z + (size_t)(rb + r) * 128 + k0 + c2);
      sA[r * 34 + c2]     = v.x;
      sA[r * 34 + c2 + 1] = v.y;
    }
#pragma unroll
    for (int it = 0; it < 4; ++it) {
      int i  = tid + it * 256;
      int r  = i >> 5;
      int c4 = (i & 31) * 4;
      float4 v = *(const float4*)(Wi + (size_t)(k0 + r) * 768 + cb + c4);
      *(float4*)(&sB[r * 132 + c4]) = v;
    }
    __syncthreads();
#pragma unroll
    for (int kk = 0; kk < 32; ++kk) {
      float a[8], b[8];
#pragma unroll
      for (int i = 0; i < 8; ++i) a[i] = sA[(rg * 8 + i) * 34 + kk];
      float4 b0 = *(const float4*)(&sB[kk * 132 + cg * 8]);
      float4 b1 = *(const float4*)(&sB[kk * 132 + cg * 8 + 4]);
      b[0] = b0.x; b[1] = b0.y; b[2] = b0.z; b[3] = b0.w;
      b[4] = b1.x; b[5] = b1.y; b[6] = b1.z; b[7] = b1.w;
#pragma unroll
      for (int i = 0; i < 8; ++i)
#pragma unroll
        for (int j = 0; j < 8; ++j) acc[i][j] = fmaf(a[i], b[j], acc[i][j]);
    }
    __syncthreads();
  }
#pragma unroll
  for (int i = 0; i < 8; ++i) {
    int row = rb + rg * 8 + i;
#pragma unroll
    for (int j = 0; j < 8; ++j) {
      int col = cb + cg * 8 + j;
      xp[(size_t)row * 768 + col] = (_Float16)(acc[i][j] + bi[col]);
    }
  }
}

// ---------------------------------------------------------------------------
// Kernel 2b: WhT f16 pack for GRU
// ---------------------------------------------------------------------------
__global__ __launch_bounds__(256) void whT_kernel(const float* __restrict__ Wh,
                                                  unsigned int* __restrict__ whT) {
  int g = blockIdx.x * 256 + threadIdx.x;  // 0..98303
  int i = g / 768;
  int j = g % 768;
  float lo = Wh[(size_t)(2 * i) * 768 + j];
  float hi = Wh[(size_t)(2 * i + 1) * 768 + j];
  whT[(size_t)j * 128 + i] = pack2(lo, hi);
}

// ---------------------------------------------------------------------------
// Kernel 2c: wkT16[k][d][c] = f16(Wk_w[k][c][d])
// ---------------------------------------------------------------------------
__global__ __launch_bounds__(256) void wkT_kernel(const float* __restrict__ Wk_w,
                                                  _Float16* __restrict__ wkT) {
  int id = blockIdx.x * 256 + threadIdx.x;  // 0..393215
  int k = id >> 15;
  int rem = id & 32767;
  int c = rem >> 7;
  int d = rem & 127;
  wkT[((size_t)k * 128 + d) * 256 + c] = (_Float16)Wk_w[id];
}

// ---------------------------------------------------------------------------
// Kernel 3: GRU scan (f16 register-resident Wh); also writes c16 f16 copy.
// ---------------------------------------------------------------------------
__global__ __launch_bounds__(768) void gru_kernel(const _Float16* __restrict__ xp,
                                                  const unsigned int* __restrict__ whT,
                                                  const float* __restrict__ bh,
                                                  float* __restrict__ c_out,
                                                  unsigned int* __restrict__ c16u) {
  __shared__ __align__(16) unsigned int s_h2[128];
  __shared__ float s_hg[768];
  __shared__ float s_xg[768];
  int j = threadIdx.x;
  int b = blockIdx.x;

  unsigned int w[128];
  const uint4* wsrc = (const uint4*)(whT + (size_t)j * 128);
#pragma unroll
  for (int i = 0; i < 32; ++i) {
    uint4 v = wsrc[i];
    w[4 * i + 0] = v.x; w[4 * i + 1] = v.y; w[4 * i + 2] = v.z; w[4 * i + 3] = v.w;
  }

  if (j < 128) s_h2[j] = 0u;
  float bhj = bh[j];
  float h0 = 0.f, h1 = 0.f;
  const _Float16* xrow = xp + (size_t)b * 512 * 768 + j;
  float x_next = (float)xrow[0];
  __syncthreads();

  for (int t = 0; t < 512; ++t) {
    float x_cur = x_next;
    if (t < 511) x_next = (float)xrow[(size_t)(t + 1) * 768];

    float acc = bhj;
    const uint4* h4 = (const uint4*)s_h2;
#pragma unroll
    for (int i = 0; i < 32; ++i) {
      uint4 hh = h4[i];
      acc = dot2acc(w[4 * i + 0], hh.x, acc);
      acc = dot2acc(w[4 * i + 1], hh.y, acc);
      acc = dot2acc(w[4 * i + 2], hh.z, acc);
      acc = dot2acc(w[4 * i + 3], hh.w, acc);
    }
    s_hg[j] = acc;
    s_xg[j] = x_cur;
    __syncthreads();

    if (j < 128) {
      int c0 = 2 * j;
      float r0 = 1.f / (1.f + __expf(-(s_xg[c0]       + s_hg[c0])));
      float z0 = 1.f / (1.f + __expf(-(s_xg[c0 + 256] + s_hg[c0 + 256])));
      float n0 = tanhf(s_xg[c0 + 512] + r0 * s_hg[c0 + 512]);
      h0 = (1.f - z0) * n0 + z0 * h0;
      float r1 = 1.f / (1.f + __expf(-(s_xg[c0 + 1]   + s_hg[c0 + 1])));
      float z1 = 1.f / (1.f + __expf(-(s_xg[c0 + 257] + s_hg[c0 + 257])));
      float n1 = tanhf(s_xg[c0 + 513] + r1 * s_hg[c0 + 513]);
      h1 = (1.f - z1) * n1 + z1 * h1;

      unsigned int hp = pack2(h0, h1);
      s_h2[j] = hp;
      *(float2*)(c_out + ((size_t)b * 512 + t) * 256 + c0) = make_float2(h0, h1);
      c16u[((size_t)b * 512 + t) * 128 + j] = hp;
    }
    __syncthreads();
  }
}

// ---------------------------------------------------------------------------
// Kernel 4: MFMA-f16 fused CPC loss.
// Phase B computes P^T (m=d, n=b): A = Wk^T[d][c] (LDS), B = Ct[b][c] (LDS).
// C/D lane layout (col=lane&15, row=4*quad+reg) -> 4 consecutive d per lane
// -> ds_write_b64 into row-major Pn[b][d] (A-operand layout for phase D).
// Phase D: L[b][c2] = Pn @ Zf^T: A = Pn[b][d], B^T = Zf[c2][d] (LDS).
// ---------------------------------------------------------------------------
__global__ __launch_bounds__(256, 2) void cpc_kernel(const _Float16* __restrict__ z16,
                                                     const _Float16* __restrict__ c16,
                                                     const _Float16* __restrict__ wkT,
                                                     const float* __restrict__ Wk_b,
                                                     float* __restrict__ out) {
  int k   = blockIdx.x;   // 0..11
  int t   = blockIdx.y;   // 0..499
  int tid = threadIdx.x;
  int wv   = tid >> 6;
  int lane = tid & 63;
  int n15  = lane & 15;
  int q    = lane >> 4;

  __shared__ __align__(16) _Float16 sA[128 * 72];     // A panels / Zf panel 0
  __shared__ __align__(16) _Float16 sB[128 * 72];     // B panels / Zf panel 1
  __shared__ __align__(16) _Float16 sP[128 * 136];    // Pn[b][d] row-major
  __shared__ float s_bias[128];

  if (tid < 128) s_bias[tid] = Wk_b[k * 128 + tid];

  f32x4 acc[2][8];   // [ntl(b-tile)][mt(d-tile)]
#pragma unroll
  for (int a = 0; a < 2; ++a)
#pragma unroll
    for (int m = 0; m < 8; ++m) acc[a][m] = (f32x4){0.f, 0.f, 0.f, 0.f};

  const _Float16* wk_base = wkT + (size_t)k * 128 * 256;

  // ---- Phase B: 4 c-panels of 64 ----
  for (int p = 0; p < 4; ++p) {
#pragma unroll
    for (int it = 0; it < 4; ++it) {
      int id = tid + it * 256;         // 0..1023
      int r  = id >> 3;                // 0..127
      int c8 = (id & 7) * 8;           // 0..56
      *(uint4*)(&sA[r * 72 + c8]) =
          *(const uint4*)(wk_base + (size_t)r * 256 + p * 64 + c8);
      *(uint4*)(&sB[r * 72 + c8]) =
          *(const uint4*)(c16 + ((size_t)r * 512 + t) * 256 + p * 64 + c8);
    }
    __syncthreads();
#pragma unroll
    for (int ks = 0; ks < 2; ++ks) {
      f16x8 bf[2];
#pragma unroll
      for (int ntl = 0; ntl < 2; ++ntl)
        bf[ntl] = *(const f16x8*)(&sB[((wv * 2 + ntl) * 16 + n15) * 72 + ks * 32 + q * 8]);
#pragma unroll
      for (int mt = 0; mt < 8; ++mt) {
        f16x8 af = *(const f16x8*)(&sA[(mt * 16 + n15) * 72 + ks * 32 + q * 8]);
        acc[0][mt] = __builtin_amdgcn_mfma_f32_16x16x32_f16(af, bf[0], acc[0][mt], 0, 0, 0);
        acc[1][mt] = __builtin_amdgcn_mfma_f32_16x16x32_f16(af, bf[1], acc[1][mt], 0, 0, 0);
      }
    }
    __syncthreads();
  }

  // ---- bias + l2norm scale (reduce over d within lane, then across quads) ----
  float scale[2];
#pragma unroll
  for (int ntl = 0; ntl < 2; ++ntl) {
    float ssq = 0.f;
#pragma unroll
    for (int mt = 0; mt < 8; ++mt)
#pragma unroll
      for (int r = 0; r < 4; ++r) {
        float v = acc[ntl][mt][r] + s_bias[mt * 16 + q * 4 + r];
        acc[ntl][mt][r] = v;
        ssq = fmaf(v, v, ssq);
      }
    ssq += __shfl_xor(ssq, 16);
    ssq += __shfl_xor(ssq, 32);
    scale[ntl] = 10.0f / fmaxf(sqrtf(ssq), 1e-12f);   // 1/TEMP folded in
  }

  // ---- write Pn[b][d] (f16, row-major, pitch 136) ----
#pragma unroll
  for (int ntl = 0; ntl < 2; ++ntl) {
    int bi = (wv * 2 + ntl) * 16 + n15;
#pragma unroll
    for (int mt = 0; mt < 8; ++mt) {
      uint2 v;
      v.x = pack2(acc[ntl][mt][0] * scale[ntl], acc[ntl][mt][1] * scale[ntl]);
      v.y = pack2(acc[ntl][mt][2] * scale[ntl], acc[ntl][mt][3] * scale[ntl]);
      *(uint2*)(&sP[bi * 136 + mt * 16 + q * 4]) = v;
    }
  }

  // ---- stage Zf: sA = d 0..63, sB = d 64..127 ----
  int tz = t + k + 1;
#pragma unroll
  for (int it = 0; it < 4; ++it) {
    int id = tid + it * 256;
    int r  = id >> 3;
    int d8 = (id & 7) * 8;
    *(uint4*)(&sA[r * 72 + d8]) =
        *(const uint4*)(z16 + ((size_t)r * 512 + tz) * 128 + d8);
    *(uint4*)(&sB[r * 72 + d8]) =
        *(const uint4*)(z16 + ((size_t)r * 512 + tz) * 128 + 64 + d8);
  }
  __syncthreads();

  // ---- Phase D: logits ----
  f32x4 lacc[2][8];   // [mtl(b-tile)][nt(c2-tile)]
#pragma unroll
  for (int a = 0; a < 2; ++a)
#pragma unroll
    for (int m = 0; m < 8; ++m) lacc[a][m] = (f32x4){0.f, 0.f, 0.f, 0.f};

#pragma unroll
  for (int pan = 0; pan < 2; ++pan) {
#pragma unroll
    for (int ks = 0; ks < 2; ++ks) {
      f16x8 af[2];
#pragma unroll
      for (int mtl = 0; mtl < 2; ++mtl)
        af[mtl] = *(const f16x8*)(&sP[((wv * 2 + mtl) * 16 + n15) * 136 + pan * 64 + ks * 32 + q * 8]);
#pragma unroll
      for (int nt = 0; nt < 8; ++nt) {
        f16x8 bf = pan
          ? *(const f16x8*)(&sB[(nt * 16 + n15) * 72 + ks * 32 + q * 8])
          : *(const f16x8*)(&sA[(nt * 16 + n15) * 72 + ks * 32 + q * 8]);
        lacc[0][nt] = __builtin_amdgcn_mfma_f32_16x16x32_f16(af[0], bf, lacc[0][nt], 0, 0, 0);
        lacc[1][nt] = __builtin_amdgcn_mfma_f32_16x16x32_f16(af[1], bf, lacc[1][nt], 0, 0, 0);
      }
    }
  }

  // ---- per-row softmax stats + diag + argmax (shuffle over low-4 lane bits) --
  float loss_acc = 0.f, corr_acc = 0.f;
#pragma unroll
  for (int mtl = 0; mtl < 2; ++mtl) {
    int dnt = wv * 2 + mtl;
#pragma unroll
    for (int r = 0; r < 4; ++r) {
      int b = (wv * 2 + mtl) * 16 + q * 4 + r;
      float m = -1e30f; int idx = 1 << 30; float diag = 0.f;
#pragma unroll
      for (int nt = 0; nt < 8; ++nt) {
        float v = lacc[mtl][nt][r];
        int c2 = nt * 16 + n15;
        if (v > m) { m = v; idx = c2; }
        if (nt == dnt && n15 == (b & 15)) diag = v;
      }
#pragma unroll
      for (int s = 1; s <= 8; s <<= 1) {
        float om = __shfl_xor(m, s);
        int   oi = __shfl_xor(idx, s);
        if (om > m || (om == m && oi < idx)) { m = om; idx = oi; }
      }
      float e = 0.f;
#pragma unroll
      for (int nt = 0; nt < 8; ++nt) e += __expf(lacc[mtl][nt][r] - m);
#pragma unroll
      for (int s = 1; s <= 8; s <<= 1) e += __shfl_xor(e, s);
      if (n15 == (b & 15)) {
        float lse = m + __logf(e);
        loss_acc += lse - diag;
        corr_acc += (idx == b) ? 1.0f : 0.0f;
      }
    }
  }
#pragma unroll
  for (int s = 1; s <= 32; s <<= 1) {
    loss_acc += __shfl_xor(loss_acc, s);
    corr_acc += __shfl_xor(corr_acc, s);
  }
  if (lane == 0) {
    atomicAdd(out + 0, loss_acc * (float)(1.0 / (double)N_SAMPLES));
    atomicAdd(out + 1, corr_acc * (float)(100.0 / (double)N_SAMPLES));
  }
}

// ---------------------------------------------------------------------------
extern "C" void kernel_launch(void* const* d_in, const int* in_sizes, int n_in,
                              void* d_out, int out_size, void* d_ws, size_t ws_size,
                              hipStream_t stream) {
  (void)in_sizes; (void)n_in; (void)out_size; (void)ws_size;
  const float* rr  = (const float*)d_in[0];
  const float* We  = (const float*)d_in[1];
  const float* be  = (const float*)d_in[2];
  const float* Wi  = (const float*)d_in[3];
  const float* Wh  = (const float*)d_in[4];
  const float* bi  = (const float*)d_in[5];
  const float* bh  = (const float*)d_in[6];
  const float* Wkw = (const float*)d_in[7];
  const float* Wkb = (const float*)d_in[8];

  float* out = (float*)d_out;
  float* z   = out + 2;                              // (B,T,D) fp32
  float* c   = z + (size_t)B_ * T_ * D_;             // (B,T,C) fp32

  // workspace layout
  char* ws = (char*)d_ws;
  unsigned int* whT   = (unsigned int*)ws;                               // 384 KB
  _Float16*     wkT16 = (_Float16*)(ws + 393216);                        // 768 KB
  _Float16*     z16   = (_Float16*)(ws + 393216 + 786432);               // 16 MB
  _Float16*     c16   = (_Float16*)(ws + 393216 + 786432 + 16777216);    // 32 MB
  _Float16*     xp    = (_Float16*)(ws + 393216 + 786432 + 16777216 + 33554432);

  hipMemsetAsync(d_out, 0, 2 * sizeof(float), stream);
  z_kernel<<<B_ * T_, 128, 0, stream>>>(rr, We, be, z, z16);
  xproj_kernel<<<dim3(512, 6), 256, 0, stream>>>(z, Wi, bi, xp);
  whT_kernel<<<384, 256, 0, stream>>>(Wh, whT);
  wkT_kernel<<<1536, 256, 0, stream>>>(Wkw, wkT16);
  gru_kernel<<<B_, 768, 0, stream>>>(xp, whT, bh, c, (unsigned int*)c16);
  cpc_kernel<<<dim3(K_, TP_), 256, 0, stream>>>(z16, c16, wkT16, Wkb, out);
}

// Round 5
// 1679.763 us; speedup vs baseline: 3.7997x; 1.0579x over previous
//
#include <hip/hip_runtime.h>
#include <math.h>

// Problem constants
#define B_  128
#define T_  512
#define W_  64
#define D_  128
#define C_  256
#define K_  12
#define TP_ 500           // T - K_STEPS
#define N_SAMPLES 768000  // K_ * TP_ * B_

typedef _Float16 half2v __attribute__((ext_vector_type(2)));
typedef _Float16 f16x8  __attribute__((ext_vector_type(8)));
typedef float    f32x4  __attribute__((ext_vector_type(4)));

#if defined(__has_builtin)
#if __has_builtin(__builtin_amdgcn_fdot2)
#define HAVE_FDOT2 1
#endif
#endif

__device__ __forceinline__ float dot2acc(unsigned int wu, unsigned int hu, float acc) {
#ifdef HAVE_FDOT2
  return __builtin_amdgcn_fdot2(__builtin_bit_cast(half2v, wu),
                                __builtin_bit_cast(half2v, hu), acc, false);
#else
  half2v w = __builtin_bit_cast(half2v, wu);
  half2v h = __builtin_bit_cast(half2v, hu);
  acc = fmaf((float)w.x, (float)h.x, acc);
  return fmaf((float)w.y, (float)h.y, acc);
#endif
}

__device__ __forceinline__ unsigned int pack2(float a, float b) {
  unsigned short ua = __builtin_bit_cast(unsigned short, (_Float16)a);
  unsigned short ub = __builtin_bit_cast(unsigned short, (_Float16)b);
  return (unsigned int)ua | ((unsigned int)ub << 16);
}

// ---------------------------------------------------------------------------
// Kernel 1: z_seq = l2norm(rr_windows @ We + be); also writes f16 copy z16.
// ---------------------------------------------------------------------------
__global__ __launch_bounds__(128) void z_kernel(const float* __restrict__ rr,
                                                const float* __restrict__ We,
                                                const float* __restrict__ be,
                                                float* __restrict__ z_out,
                                                _Float16* __restrict__ z16) {
  int row = blockIdx.x;   // b*T + t
  int d   = threadIdx.x;  // 0..127
  __shared__ float s_rr[64];
  __shared__ float s_red[128];
  if (d < 64) s_rr[d] = rr[row * 64 + d];
  __syncthreads();
  float acc = be[d];
#pragma unroll
  for (int w = 0; w < 64; ++w) acc = fmaf(s_rr[w], We[w * 128 + d], acc);
  s_red[d] = acc * acc;
  __syncthreads();
#pragma unroll
  for (int s = 64; s > 0; s >>= 1) {
    if (d < s) s_red[d] += s_red[d + s];
    __syncthreads();
  }
  float inv = 1.0f / fmaxf(sqrtf(s_red[0]), 1e-12f);
  float zv = acc * inv;
  z_out[row * 128 + d] = zv;
  z16[(size_t)row * 128 + d] = (_Float16)zv;
}

// ---------------------------------------------------------------------------
// Kernel 2a: wiT16[col][k] = f16(Wi[k][col])  (for MFMA B operand)
// ---------------------------------------------------------------------------
__global__ __launch_bounds__(256) void wiT_kernel(const float* __restrict__ Wi,
                                                  _Float16* __restrict__ wiT) {
  int id = blockIdx.x * 256 + threadIdx.x;  // 0..98303
  int k   = id / 768;
  int col = id % 768;
  wiT[(size_t)col * 128 + k] = (_Float16)Wi[id];
}

// ---------------------------------------------------------------------------
// Kernel 2: x_proj = z_seq @ Wi + bi (MFMA f16, stored f16).
// Mirrors cpc Phase-B fragment pattern (proven in R3): A[m][k] = z16 rows,
// B[n][k] = wiT cols, both k-contiguous; D row = q*4+reg (m), col = n15 (n).
// ---------------------------------------------------------------------------
__global__ __launch_bounds__(256, 2) void xproj_mfma(const _Float16* __restrict__ z16,
                                                     const _Float16* __restrict__ wiT,
                                                     const float* __restrict__ bi,
                                                     _Float16* __restrict__ xp) {
  int rb  = blockIdx.x * 128;   // row tile base (65536 rows)
  int cb  = blockIdx.y * 128;   // col tile base (768 cols)
  int tid  = threadIdx.x;
  int wv   = tid >> 6;
  int lane = tid & 63;
  int n15  = lane & 15;
  int q    = lane >> 4;

  __shared__ __align__(16) _Float16 sA[128 * 72];   // z rows   [m][64-k panel]
  __shared__ __align__(16) _Float16 sB[128 * 72];   // wiT cols [n][64-k panel]

  f32x4 acc[2][8];
#pragma unroll
  for (int a = 0; a < 2; ++a)
#pragma unroll
    for (int m = 0; m < 8; ++m) acc[a][m] = (f32x4){0.f, 0.f, 0.f, 0.f};

#pragma unroll
  for (int p = 0; p < 2; ++p) {   // K=128 in 2 panels of 64
#pragma unroll
    for (int it = 0; it < 4; ++it) {
      int id = tid + it * 256;    // 0..1023
      int r  = id >> 3;           // 0..127
      int c8 = (id & 7) * 8;      // 0..56
      *(uint4*)(&sA[r * 72 + c8]) =
          *(const uint4*)(z16 + (size_t)(rb + r) * 128 + p * 64 + c8);
      *(uint4*)(&sB[r * 72 + c8]) =
          *(const uint4*)(wiT + (size_t)(cb + r) * 128 + p * 64 + c8);
    }
    __syncthreads();
#pragma unroll
    for (int ks = 0; ks < 2; ++ks) {
      f16x8 bf[2];
#pragma unroll
      for (int ntl = 0; ntl < 2; ++ntl)
        bf[ntl] = *(const f16x8*)(&sB[((wv * 2 + ntl) * 16 + n15) * 72 + ks * 32 + q * 8]);
#pragma unroll
      for (int mt = 0; mt < 8; ++mt) {
        f16x8 af = *(const f16x8*)(&sA[(mt * 16 + n15) * 72 + ks * 32 + q * 8]);
        acc[0][mt] = __builtin_amdgcn_mfma_f32_16x16x32_f16(af, bf[0], acc[0][mt], 0, 0, 0);
        acc[1][mt] = __builtin_amdgcn_mfma_f32_16x16x32_f16(af, bf[1], acc[1][mt], 0, 0, 0);
      }
    }
    __syncthreads();
  }

  // epilogue: bias + f16 store
#pragma unroll
  for (int ntl = 0; ntl < 2; ++ntl) {
    int col = cb + (wv * 2 + ntl) * 16 + n15;
    float bb = bi[col];
#pragma unroll
    for (int mt = 0; mt < 8; ++mt) {
#pragma unroll
      for (int r = 0; r < 4; ++r) {
        int row = rb + mt * 16 + q * 4 + r;
        xp[(size_t)row * 768 + col] = (_Float16)(acc[ntl][mt][r] + bb);
      }
    }
  }
}

// ---------------------------------------------------------------------------
// Kernel 2b: WhT f16 pack for GRU
// ---------------------------------------------------------------------------
__global__ __launch_bounds__(256) void whT_kernel(const float* __restrict__ Wh,
                                                  unsigned int* __restrict__ whT) {
  int g = blockIdx.x * 256 + threadIdx.x;  // 0..98303
  int i = g / 768;
  int j = g % 768;
  float lo = Wh[(size_t)(2 * i) * 768 + j];
  float hi = Wh[(size_t)(2 * i + 1) * 768 + j];
  whT[(size_t)j * 128 + i] = pack2(lo, hi);
}

// ---------------------------------------------------------------------------
// Kernel 2c: wkT16[k][d][c] = f16(Wk_w[k][c][d])
// ---------------------------------------------------------------------------
__global__ __launch_bounds__(256) void wkT_kernel(const float* __restrict__ Wk_w,
                                                  _Float16* __restrict__ wkT) {
  int id = blockIdx.x * 256 + threadIdx.x;  // 0..393215
  int k = id >> 15;
  int rem = id & 32767;
  int c = rem >> 7;
  int d = rem & 127;
  wkT[((size_t)k * 128 + d) * 256 + c] = (_Float16)Wk_w[id];
}

// ---------------------------------------------------------------------------
// Kernel 3: GRU scan (EXACT R3 version — proven through full harness).
// 128 blocks x 768 threads, 1 row/block; w[128] lands in AGPRs (VGPR=84).
// ---------------------------------------------------------------------------
__global__ __launch_bounds__(768) void gru_kernel(const _Float16* __restrict__ xp,
                                                  const unsigned int* __restrict__ whT,
                                                  const float* __restrict__ bh,
                                                  float* __restrict__ c_out,
                                                  unsigned int* __restrict__ c16u) {
  __shared__ __align__(16) unsigned int s_h2[128];
  __shared__ float s_hg[768];
  __shared__ float s_xg[768];
  int j = threadIdx.x;
  int b = blockIdx.x;

  unsigned int w[128];
  const uint4* wsrc = (const uint4*)(whT + (size_t)j * 128);
#pragma unroll
  for (int i = 0; i < 32; ++i) {
    uint4 v = wsrc[i];
    w[4 * i + 0] = v.x; w[4 * i + 1] = v.y; w[4 * i + 2] = v.z; w[4 * i + 3] = v.w;
  }

  if (j < 128) s_h2[j] = 0u;
  float bhj = bh[j];
  float h0 = 0.f, h1 = 0.f;
  const _Float16* xrow = xp + (size_t)b * 512 * 768 + j;
  float x_next = (float)xrow[0];
  __syncthreads();

  for (int t = 0; t < 512; ++t) {
    float x_cur = x_next;
    if (t < 511) x_next = (float)xrow[(size_t)(t + 1) * 768];

    float acc = bhj;
    const uint4* h4 = (const uint4*)s_h2;
#pragma unroll
    for (int i = 0; i < 32; ++i) {
      uint4 hh = h4[i];
      acc = dot2acc(w[4 * i + 0], hh.x, acc);
      acc = dot2acc(w[4 * i + 1], hh.y, acc);
      acc = dot2acc(w[4 * i + 2], hh.z, acc);
      acc = dot2acc(w[4 * i + 3], hh.w, acc);
    }
    s_hg[j] = acc;
    s_xg[j] = x_cur;
    __syncthreads();

    if (j < 128) {
      int c0 = 2 * j;
      float r0 = 1.f / (1.f + __expf(-(s_xg[c0]       + s_hg[c0])));
      float z0 = 1.f / (1.f + __expf(-(s_xg[c0 + 256] + s_hg[c0 + 256])));
      float n0 = tanhf(s_xg[c0 + 512] + r0 * s_hg[c0 + 512]);
      h0 = (1.f - z0) * n0 + z0 * h0;
      float r1 = 1.f / (1.f + __expf(-(s_xg[c0 + 1]   + s_hg[c0 + 1])));
      float z1 = 1.f / (1.f + __expf(-(s_xg[c0 + 257] + s_hg[c0 + 257])));
      float n1 = tanhf(s_xg[c0 + 513] + r1 * s_hg[c0 + 513]);
      h1 = (1.f - z1) * n1 + z1 * h1;

      unsigned int hp = pack2(h0, h1);
      s_h2[j] = hp;
      *(float2*)(c_out + ((size_t)b * 512 + t) * 256 + c0) = make_float2(h0, h1);
      c16u[((size_t)b * 512 + t) * 128 + j] = hp;
    }
    __syncthreads();
  }
}

// ---------------------------------------------------------------------------
// Kernel 4: MFMA-f16 fused CPC loss (EXACT R3 version — proven).
// ---------------------------------------------------------------------------
__global__ __launch_bounds__(256, 2) void cpc_kernel(const _Float16* __restrict__ z16,
                                                     const _Float16* __restrict__ c16,
                                                     const _Float16* __restrict__ wkT,
                                                     const float* __restrict__ Wk_b,
                                                     float* __restrict__ out) {
  int k   = blockIdx.x;   // 0..11
  int t   = blockIdx.y;   // 0..499
  int tid = threadIdx.x;
  int wv   = tid >> 6;
  int lane = tid & 63;
  int n15  = lane & 15;
  int q    = lane >> 4;

  __shared__ __align__(16) _Float16 sA[128 * 72];
  __shared__ __align__(16) _Float16 sB[128 * 72];
  __shared__ __align__(16) _Float16 sP[128 * 136];
  __shared__ float s_bias[128];

  if (tid < 128) s_bias[tid] = Wk_b[k * 128 + tid];

  f32x4 acc[2][8];
#pragma unroll
  for (int a = 0; a < 2; ++a)
#pragma unroll
    for (int m = 0; m < 8; ++m) acc[a][m] = (f32x4){0.f, 0.f, 0.f, 0.f};

  const _Float16* wk_base = wkT + (size_t)k * 128 * 256;

  // ---- Phase B: P^T = Wk^T @ Ct^T, 4 c-panels of 64 ----
  for (int p = 0; p < 4; ++p) {
#pragma unroll
    for (int it = 0; it < 4; ++it) {
      int id = tid + it * 256;
      int r  = id >> 3;
      int c8 = (id & 7) * 8;
      *(uint4*)(&sA[r * 72 + c8]) =
          *(const uint4*)(wk_base + (size_t)r * 256 + p * 64 + c8);
      *(uint4*)(&sB[r * 72 + c8]) =
          *(const uint4*)(c16 + ((size_t)r * 512 + t) * 256 + p * 64 + c8);
    }
    __syncthreads();
#pragma unroll
    for (int ks = 0; ks < 2; ++ks) {
      f16x8 bf[2];
#pragma unroll
      for (int ntl = 0; ntl < 2; ++ntl)
        bf[ntl] = *(const f16x8*)(&sB[((wv * 2 + ntl) * 16 + n15) * 72 + ks * 32 + q * 8]);
#pragma unroll
      for (int mt = 0; mt < 8; ++mt) {
        f16x8 af = *(const f16x8*)(&sA[(mt * 16 + n15) * 72 + ks * 32 + q * 8]);
        acc[0][mt] = __builtin_amdgcn_mfma_f32_16x16x32_f16(af, bf[0], acc[0][mt], 0, 0, 0);
        acc[1][mt] = __builtin_amdgcn_mfma_f32_16x16x32_f16(af, bf[1], acc[1][mt], 0, 0, 0);
      }
    }
    __syncthreads();
  }

  // ---- bias + l2norm scale ----
  float scale[2];
#pragma unroll
  for (int ntl = 0; ntl < 2; ++ntl) {
    float ssq = 0.f;
#pragma unroll
    for (int mt = 0; mt < 8; ++mt)
#pragma unroll
      for (int r = 0; r < 4; ++r) {
        float v = acc[ntl][mt][r] + s_bias[mt * 16 + q * 4 + r];
        acc[ntl][mt][r] = v;
        ssq = fmaf(v, v, ssq);
      }
    ssq += __shfl_xor(ssq, 16);
    ssq += __shfl_xor(ssq, 32);
    scale[ntl] = 10.0f / fmaxf(sqrtf(ssq), 1e-12f);
  }

  // ---- write Pn[b][d] ----
#pragma unroll
  for (int ntl = 0; ntl < 2; ++ntl) {
    int bi = (wv * 2 + ntl) * 16 + n15;
#pragma unroll
    for (int mt = 0; mt < 8; ++mt) {
      uint2 v;
      v.x = pack2(acc[ntl][mt][0] * scale[ntl], acc[ntl][mt][1] * scale[ntl]);
      v.y = pack2(acc[ntl][mt][2] * scale[ntl], acc[ntl][mt][3] * scale[ntl]);
      *(uint2*)(&sP[bi * 136 + mt * 16 + q * 4]) = v;
    }
  }

  // ---- stage Zf ----
  int tz = t + k + 1;
#pragma unroll
  for (int it = 0; it < 4; ++it) {
    int id = tid + it * 256;
    int r  = id >> 3;
    int d8 = (id & 7) * 8;
    *(uint4*)(&sA[r * 72 + d8]) =
        *(const uint4*)(z16 + ((size_t)r * 512 + tz) * 128 + d8);
    *(uint4*)(&sB[r * 72 + d8]) =
        *(const uint4*)(z16 + ((size_t)r * 512 + tz) * 128 + 64 + d8);
  }
  __syncthreads();

  // ---- Phase D: logits ----
  f32x4 lacc[2][8];
#pragma unroll
  for (int a = 0; a < 2; ++a)
#pragma unroll
    for (int m = 0; m < 8; ++m) lacc[a][m] = (f32x4){0.f, 0.f, 0.f, 0.f};

#pragma unroll
  for (int pan = 0; pan < 2; ++pan) {
#pragma unroll
    for (int ks = 0; ks < 2; ++ks) {
      f16x8 af[2];
#pragma unroll
      for (int mtl = 0; mtl < 2; ++mtl)
        af[mtl] = *(const f16x8*)(&sP[((wv * 2 + mtl) * 16 + n15) * 136 + pan * 64 + ks * 32 + q * 8]);
#pragma unroll
      for (int nt = 0; nt < 8; ++nt) {
        f16x8 bf = pan
          ? *(const f16x8*)(&sB[(nt * 16 + n15) * 72 + ks * 32 + q * 8])
          : *(const f16x8*)(&sA[(nt * 16 + n15) * 72 + ks * 32 + q * 8]);
        lacc[0][nt] = __builtin_amdgcn_mfma_f32_16x16x32_f16(af[0], bf, lacc[0][nt], 0, 0, 0);
        lacc[1][nt] = __builtin_amdgcn_mfma_f32_16x16x32_f16(af[1], bf, lacc[1][nt], 0, 0, 0);
      }
    }
  }

  // ---- softmax stats + diag + argmax ----
  float loss_acc = 0.f, corr_acc = 0.f;
#pragma unroll
  for (int mtl = 0; mtl < 2; ++mtl) {
    int dnt = wv * 2 + mtl;
#pragma unroll
    for (int r = 0; r < 4; ++r) {
      int b = (wv * 2 + mtl) * 16 + q * 4 + r;
      float m = -1e30f; int idx = 1 << 30; float diag = 0.f;
#pragma unroll
      for (int nt = 0; nt < 8; ++nt) {
        float v = lacc[mtl][nt][r];
        int c2 = nt * 16 + n15;
        if (v > m) { m = v; idx = c2; }
        if (nt == dnt && n15 == (b & 15)) diag = v;
      }
#pragma unroll
      for (int s = 1; s <= 8; s <<= 1) {
        float om = __shfl_xor(m, s);
        int   oi = __shfl_xor(idx, s);
        if (om > m || (om == m && oi < idx)) { m = om; idx = oi; }
      }
      float e = 0.f;
#pragma unroll
      for (int nt = 0; nt < 8; ++nt) e += __expf(lacc[mtl][nt][r] - m);
#pragma unroll
      for (int s = 1; s <= 8; s <<= 1) e += __shfl_xor(e, s);
      if (n15 == (b & 15)) {
        float lse = m + __logf(e);
        loss_acc += lse - diag;
        corr_acc += (idx == b) ? 1.0f : 0.0f;
      }
    }
  }
#pragma unroll
  for (int s = 1; s <= 32; s <<= 1) {
    loss_acc += __shfl_xor(loss_acc, s);
    corr_acc += __shfl_xor(corr_acc, s);
  }
  if (lane == 0) {
    atomicAdd(out + 0, loss_acc * (float)(1.0 / (double)N_SAMPLES));
    atomicAdd(out + 1, corr_acc * (float)(100.0 / (double)N_SAMPLES));
  }
}

// ---------------------------------------------------------------------------
extern "C" void kernel_launch(void* const* d_in, const int* in_sizes, int n_in,
                              void* d_out, int out_size, void* d_ws, size_t ws_size,
                              hipStream_t stream) {
  (void)in_sizes; (void)n_in; (void)out_size; (void)ws_size;
  const float* rr  = (const float*)d_in[0];
  const float* We  = (const float*)d_in[1];
  const float* be  = (const float*)d_in[2];
  const float* Wi  = (const float*)d_in[3];
  const float* Wh  = (const float*)d_in[4];
  const float* bi  = (const float*)d_in[5];
  const float* bh  = (const float*)d_in[6];
  const float* Wkw = (const float*)d_in[7];
  const float* Wkb = (const float*)d_in[8];

  float* out = (float*)d_out;
  float* z   = out + 2;                              // (B,T,D) fp32
  float* c   = z + (size_t)B_ * T_ * D_;             // (B,T,C) fp32

  // workspace layout (bytes):
  //   whT    @ 0          (384 KB)
  //   wkT16  @ 393216     (768 KB)
  //   z16    @ 1179648    (16 MB)
  //   c16    @ 17956864   (32 MB)
  //   xp     @ 51511296   (100.7 MB)
  //   wiT16  @ 152174592  (192 KB)
  char* ws = (char*)d_ws;
  unsigned int* whT   = (unsigned int*)ws;
  _Float16*     wkT16 = (_Float16*)(ws + 393216);
  _Float16*     z16   = (_Float16*)(ws + 1179648);
  _Float16*     c16   = (_Float16*)(ws + 17956864);
  _Float16*     xp    = (_Float16*)(ws + 51511296);
  _Float16*     wiT16 = (_Float16*)(ws + 152174592);

  hipMemsetAsync(d_out, 0, 2 * sizeof(float), stream);
  z_kernel<<<B_ * T_, 128, 0, stream>>>(rr, We, be, z, z16);
  wiT_kernel<<<384, 256, 0, stream>>>(Wi, wiT16);
  whT_kernel<<<384, 256, 0, stream>>>(Wh, whT);
  wkT_kernel<<<1536, 256, 0, stream>>>(Wkw, wkT16);
  xproj_mfma<<<dim3(512, 6), 256, 0, stream>>>(z16, wiT16, bi, xp);
  gru_kernel<<<B_, 768, 0, stream>>>(xp, whT, bh, c, (unsigned int*)c16);
  cpc_kernel<<<dim3(K_, TP_), 256, 0, stream>>>(z16, c16, wkT16, Wkb, out);
}